// Round 18
// baseline (368.626 us; speedup 1.0000x reference)
//
#include <hip/hip_runtime.h>
#include <cstdint>
#include <cstddef>

#define DEV __device__ __forceinline__

typedef __attribute__((ext_vector_type(8))) short bf16x8;
typedef __attribute__((ext_vector_type(4))) float f32x4;

typedef const __attribute__((address_space(1))) void gl_void;
typedef __attribute__((address_space(3))) void lds_void;

// ---------- small helpers ----------
DEV unsigned short f2bf(float f){
  union { float f; uint32_t u; } v; v.f = f;
  uint32_t r = v.u + 0x7FFFu + ((v.u >> 16) & 1u);  // RNE
  return (unsigned short)(r >> 16);
}
DEV float bf2f(unsigned short u){
  union { uint32_t u; float f; } v; v.u = ((uint32_t)u) << 16; return v.f;
}
DEV uint32_t packbf2(float a, float b){
  return (uint32_t)f2bf(a) | ((uint32_t)f2bf(b) << 16);
}

// ================= LayerNorm (bf16 in -> bf16 out) =================
__global__ void ln_bf(const unsigned short* __restrict__ x, const float* __restrict__ gw,
                      const float* __restrict__ bw, unsigned short* __restrict__ obf)
{
  const int row = blockIdx.x, t = threadIdx.x;
  const ushort4 xv = ((const ushort4*)(x + (size_t)row*1024))[t];
  float4 v; v.x = bf2f(xv.x); v.y = bf2f(xv.y); v.z = bf2f(xv.z); v.w = bf2f(xv.w);
  float s  = v.x + v.y + v.z + v.w;
  float s2 = v.x*v.x + v.y*v.y + v.z*v.z + v.w*v.w;
  #pragma unroll
  for (int o = 32; o >= 1; o >>= 1){ s += __shfl_down(s, o); s2 += __shfl_down(s2, o); }
  __shared__ float red[8];
  const int w = t >> 6, ln = t & 63;
  if (ln == 0){ red[w] = s; red[4+w] = s2; }
  __syncthreads();
  const float fs  = red[0]+red[1]+red[2]+red[3];
  const float fs2 = red[4]+red[5]+red[6]+red[7];
  const float mean = fs * (1.0f/1024.0f);
  const float var  = fs2 * (1.0f/1024.0f) - mean*mean;
  const float rstd = rsqrtf(var + 1e-5f);
  const float4 gv = ((const float4*)gw)[t];
  const float4 bv = ((const float4*)bw)[t];
  ushort4 ob;
  ob.x = f2bf((v.x-mean)*rstd*gv.x + bv.x);
  ob.y = f2bf((v.y-mean)*rstd*gv.y + bv.y);
  ob.z = f2bf((v.z-mean)*rstd*gv.z + bv.z);
  ob.w = f2bf((v.w-mean)*rstd*gv.w + bv.w);
  ((ushort4*)(obf + (size_t)row*1024))[t] = ob;
}

// ===== fused: split-K reduce (x2 = p0..p3 + x1 + b2; bf16 in/out) + LN3 =====
__global__ void reduce_ln(const unsigned short* __restrict__ p, const float* __restrict__ b2,
                          const unsigned short* __restrict__ x1, unsigned short* __restrict__ x2,
                          const float* __restrict__ g3, const float* __restrict__ b3,
                          unsigned short* __restrict__ resb, unsigned short* __restrict__ xnb)
{
  const int row = blockIdx.x, t = threadIdx.x;
  const size_t off = (size_t)row*1024/4 + t;
  const ushort4 rv = ((const ushort4*)x1)[off];
  const float4 bv2 = ((const float4*)b2)[t];
  float4 v;
  v.x = bf2f(rv.x) + bv2.x; v.y = bf2f(rv.y) + bv2.y;
  v.z = bf2f(rv.z) + bv2.z; v.w = bf2f(rv.w) + bv2.w;
  #pragma unroll
  for (int pl = 0; pl < 4; ++pl){
    const ushort4 a = ((const ushort4*)(p + (size_t)pl*4194304))[off];
    v.x += bf2f(a.x); v.y += bf2f(a.y); v.z += bf2f(a.z); v.w += bf2f(a.w);
  }
  ushort4 xo; xo.x = f2bf(v.x); xo.y = f2bf(v.y); xo.z = f2bf(v.z); xo.w = f2bf(v.w);
  ((ushort4*)x2)[off] = xo;
  float s  = v.x + v.y + v.z + v.w;
  float s2 = v.x*v.x + v.y*v.y + v.z*v.z + v.w*v.w;
  #pragma unroll
  for (int o = 32; o >= 1; o >>= 1){ s += __shfl_down(s, o); s2 += __shfl_down(s2, o); }
  __shared__ float red[8];
  const int w = t >> 6, ln = t & 63;
  if (ln == 0){ red[w] = s; red[4+w] = s2; }
  __syncthreads();
  const float fs  = red[0]+red[1]+red[2]+red[3];
  const float fs2 = red[4]+red[5]+red[6]+red[7];
  const float mean = fs * (1.0f/1024.0f);
  const float var  = fs2 * (1.0f/1024.0f) - mean*mean;
  const float rstd = rsqrtf(var + 1e-5f);
  const float4 gv = ((const float4*)g3)[t];
  const float4 bv = ((const float4*)b3)[t];
  ushort4 ob;
  ob.x = f2bf((v.x-mean)*rstd*gv.x + bv.x);
  ob.y = f2bf((v.y-mean)*rstd*gv.y + bv.y);
  ob.z = f2bf((v.z-mean)*rstd*gv.z + bv.z);
  ob.w = f2bf((v.w-mean)*rstd*gv.w + bv.w);
  ((ushort4*)resb)[off] = ob;
  ((ushort4*)xnb)[off] = ob;
}

// ================= fused weight prep + ln1 ==========
struct Ptr5 { const float* p[5]; };

DEV void dev_transpose(const float* __restrict__ src, unsigned short* __restrict__ dst,
                       int r0, int c0, int R, int C)
{
  __shared__ float tile[32][33];
  const int tx = threadIdx.x & 31, ty = threadIdx.x >> 5;   // 32 x 8
  #pragma unroll
  for (int i = 0; i < 32; i += 8)
    tile[ty+i][tx] = src[(size_t)(r0+ty+i)*C + c0 + tx];
  __syncthreads();
  #pragma unroll
  for (int i = 0; i < 32; i += 8)
    dst[(size_t)(c0+ty+i)*R + r0 + tx] = f2bf(tile[tx][ty+i]);
}

__global__ void prep_all(Ptr5 p5, unsigned short* __restrict__ wqkvgT,
                         const float* __restrict__ w1, unsigned short* __restrict__ w1T,
                         const float* __restrict__ w2, unsigned short* __restrict__ w2T,
                         const float* __restrict__ cb, unsigned short* __restrict__ cbbf,
                         float* __restrict__ cbn2, float2* __restrict__ rtab,
                         const float* __restrict__ x, const float* __restrict__ ln1_g,
                         const float* __restrict__ ln1_b, unsigned short* __restrict__ hbf)
{
  const int b = blockIdx.x, t = threadIdx.x;
  if (b < 5120){                                  // 5x 1024x1024 transpose
    const int z = b >> 10, r = b & 1023;
    dev_transpose(p5.p[z], wqkvgT + (size_t)z*1048576, (r >> 5)*32, (r & 31)*32, 1024, 1024);
  } else if (b < 9216){                           // w1 [1024][4096] -> w1T [4096][1024]
    const int r = b - 5120;
    dev_transpose(w1, w1T, (r >> 7)*32, (r & 127)*32, 1024, 4096);
  } else if (b < 13312){                          // w2 [4096][1024] -> w2T [1024][4096]
    const int r = b - 9216;
    dev_transpose(w2, w2T, (r >> 5)*32, (r & 31)*32, 4096, 1024);
  } else if (b < 17408){                          // codebook cast + norms
    const int code = b - 13312;
    const float4 v = ((const float4*)(cb + (size_t)code*1024))[t];
    ushort4 o; o.x = f2bf(v.x); o.y = f2bf(v.y); o.z = f2bf(v.z); o.w = f2bf(v.w);
    ((ushort4*)(cbbf + (size_t)code*1024))[t] = o;
    float s = v.x*v.x + v.y*v.y + v.z*v.z + v.w*v.w;
    #pragma unroll
    for (int off = 32; off >= 1; off >>= 1) s += __shfl_down(s, off);
    __shared__ float red[4];
    if ((t & 63) == 0) red[t >> 6] = s;
    __syncthreads();
    if (t == 0) cbn2[code] = red[0]+red[1]+red[2]+red[3];
  } else if (b < 17664){                          // rope table
    const int i = (b - 17408)*256 + t;            // 65536 = 2048 x 32
    const int s = i >> 5, j = i & 31;
    const float ang = (float)s * exp2f(-(float)j * 0.4152410118609203f);
    float sn, cs; sincosf(ang, &sn, &cs);
    rtab[i] = make_float2(cs, sn);
  } else {                                        // ln1
    const int row = b - 17664;
    const float4 v = ((const float4*)(x + (size_t)row*1024))[t];
    float s  = v.x + v.y + v.z + v.w;
    float s2 = v.x*v.x + v.y*v.y + v.z*v.z + v.w*v.w;
    #pragma unroll
    for (int o = 32; o >= 1; o >>= 1){ s += __shfl_down(s, o); s2 += __shfl_down(s2, o); }
    __shared__ float red2[8];
    const int w = t >> 6, ln = t & 63;
    if (ln == 0){ red2[w] = s; red2[4+w] = s2; }
    __syncthreads();
    const float fs  = red2[0]+red2[1]+red2[2]+red2[3];
    const float fs2 = red2[4]+red2[5]+red2[6]+red2[7];
    const float mean = fs * (1.0f/1024.0f);
    const float var  = fs2 * (1.0f/1024.0f) - mean*mean;
    const float rstd = rsqrtf(var + 1e-5f);
    const float4 gv = ((const float4*)ln1_g)[t];
    const float4 bv = ((const float4*)ln1_b)[t];
    ushort4 ob;
    ob.x = f2bf((v.x-mean)*rstd*gv.x + bv.x);
    ob.y = f2bf((v.y-mean)*rstd*gv.y + bv.y);
    ob.z = f2bf((v.z-mean)*rstd*gv.z + bv.z);
    ob.w = f2bf((v.w-mean)*rstd*gv.w + bv.w);
    ((ushort4*)(hbf + (size_t)row*1024))[t] = ob;
  }
}

// ===== GEMM 128x256, BK=32, 3-buf counted-vmcnt, 2 blocks/CU (72 KB LDS), 8 waves ======
// EPI: 2 = gelu+bias (bf16 out, C[M][N]); 3 = QKVG split (rope table on sects 0,1; silu on 3)
template<int EPI>
__global__ __launch_bounds__(512, 2) void gemmf(
    const unsigned short* __restrict__ A, const unsigned short* __restrict__ BT,
    unsigned short* __restrict__ C, const float* __restrict__ bias,
    const float2* __restrict__ rt, int M, int N, int K)
{
  __shared__ __align__(16) unsigned short SH[36864];
  const int t = threadIdx.x;
  const int w = t >> 6, ln = t & 63, lg = ln >> 4, lc = ln & 15;
  const int wm = w >> 2, wn = w & 3;            // 2 x 4 wave grid: 64 rows x 64 cols per wave
  const int gx = gridDim.x, nwg = gridDim.x * gridDim.y;
  int lin = blockIdx.y * gx + blockIdx.x;
  lin = (lin >> 3) + (lin & 7) * (nwg >> 3);    // chunked XCD swizzle (nwg % 8 == 0)
  const int m0 = (lin / gx) * 128, n0 = (lin % gx) * 256;
  const int nkt = K >> 5;

  f32x4 acc[4][4] = {};
  bf16x8 aF[4], bF[4];

  auto stage = [&](int buf, int kt){
    const int ub = buf*1536;
    {
      const int ro = t >> 2, cu = t & 3;
      const int su = cu ^ ((ro >> 1) & 3);
      __builtin_amdgcn_global_load_lds(
        (gl_void*)(A + (size_t)(m0+ro)*K + (size_t)kt*32 + su*8),
        (lds_void*)&SH[(ub + (t & ~63))*8], 16, 0, 0);
    }
    #pragma unroll
    for (int j = 0; j < 2; ++j){
      const int u = j*512 + t;
      const int ro = u >> 2, cu = u & 3;
      const int su = cu ^ ((ro >> 1) & 3);
      __builtin_amdgcn_global_load_lds(
        (gl_void*)(BT + (size_t)(n0+ro)*K + (size_t)kt*32 + su*8),
        (lds_void*)&SH[(ub + 512 + j*512 + (t & ~63))*8], 16, 0, 0);
    }
  };

  auto ldA = [&](int buf, int mf) -> bf16x8 {
    const int R = wm*64 + mf*16 + lc;
    const int cu = lg ^ ((R >> 1) & 3);
    return *(const bf16x8*)&SH[(buf*1536 + R*4 + cu)*8];
  };
  auto ldB = [&](int buf, int nf) -> bf16x8 {
    const int R = wn*64 + nf*16 + lc;
    const int cu = lg ^ ((R >> 1) & 3);
    return *(const bf16x8*)&SH[(buf*1536 + 512 + R*4 + cu)*8];
  };

  stage(0, 0); stage(1, 1);
  asm volatile("s_waitcnt vmcnt(3)" ::: "memory");
  __builtin_amdgcn_s_barrier();

  for (int kt = 0; kt < nkt; ++kt){
    const int cur = kt % 3;
    const bool pf = (kt + 2 < nkt);

    if (pf) stage((kt + 2) % 3, kt + 2);
    #pragma unroll
    for (int f = 0; f < 4; ++f) aF[f] = ldA(cur, f);
    bF[0] = ldB(cur, 0); bF[1] = ldB(cur, 1);
    __builtin_amdgcn_s_barrier();
    __builtin_amdgcn_s_setprio(1);
    #pragma unroll
    for (int mf = 0; mf < 4; ++mf)
      #pragma unroll
      for (int nf = 0; nf < 2; ++nf)
        acc[mf][nf] = __builtin_amdgcn_mfma_f32_16x16x32_bf16(aF[mf], bF[nf], acc[mf][nf], 0, 0, 0);
    __builtin_amdgcn_s_setprio(0);
    asm volatile("s_waitcnt lgkmcnt(0)" ::: "memory");
    __builtin_amdgcn_s_barrier();

    bF[2] = ldB(cur, 2); bF[3] = ldB(cur, 3);
    __builtin_amdgcn_s_barrier();
    __builtin_amdgcn_s_setprio(1);
    #pragma unroll
    for (int mf = 0; mf < 4; ++mf)
      #pragma unroll
      for (int nf = 2; nf < 4; ++nf)
        acc[mf][nf] = __builtin_amdgcn_mfma_f32_16x16x32_bf16(aF[mf], bF[nf], acc[mf][nf], 0, 0, 0);
    __builtin_amdgcn_s_setprio(0);
    asm volatile("s_waitcnt lgkmcnt(0)" ::: "memory");
    if (pf) asm volatile("s_waitcnt vmcnt(3)" ::: "memory");
    else    asm volatile("s_waitcnt vmcnt(0)" ::: "memory");
    __builtin_amdgcn_s_barrier();
  }

  if constexpr (EPI == 3){
    const int sect = n0 >> 10;
    unsigned short* outp = C + (size_t)sect*4194304;
    const int cb1 = n0 & 1023;
    #pragma unroll
    for (int mf = 0; mf < 4; ++mf){
      #pragma unroll
      for (int r = 0; r < 4; ++r){
        const int row = m0 + wm*64 + mf*16 + lg*4 + r;
        const int s_ = row & 2047;
        #pragma unroll
        for (int nf = 0; nf < 4; ++nf){
          const int c1 = cb1 + wn*64 + nf*16 + lc;
          float v = acc[mf][nf][r];
          if (sect <= 1){
            const float2 cs = rt[(s_ << 5) + (c1 & 31)];
            const float vp = acc[mf][nf ^ 2][r];
            v = (c1 & 32) ? (v*cs.x + vp*cs.y) : (v*cs.x - vp*cs.y);
          } else if (sect == 3){
            v = v * (1.0f / (1.0f + __expf(-v)));
          }
          outp[(size_t)row*1024 + c1] = f2bf(v);
        }
      }
    }
  } else {
    #pragma unroll
    for (int mf = 0; mf < 4; ++mf){
      #pragma unroll
      for (int r = 0; r < 4; ++r){
        const int row = m0 + wm*64 + mf*16 + lg*4 + r;
        #pragma unroll
        for (int nf = 0; nf < 4; ++nf){
          const int col = n0 + wn*64 + nf*16 + lc;
          float v = acc[mf][nf][r] + bias[col];
          v = 0.5f * v * (1.0f + erff(v * 0.70710678118654752f));
          C[(size_t)row*N + col] = f2bf(v);
        }
      }
    }
  }
}

// ===== GEMM 128x128, BK=32, m97-exact, 4 blocks/CU, split-K (bf16 partial out) =====
template<int NSPLIT>
__global__ __launch_bounds__(256, 4) void gemm128_sk(
    const unsigned short* __restrict__ A, const unsigned short* __restrict__ BT,
    unsigned short* __restrict__ Cp_base, int M, int N, int K)
{
  __shared__ __align__(16) unsigned short As[2][128*32];
  __shared__ __align__(16) unsigned short Bs[2][128*32];
  const int t = threadIdx.x;
  const int w = t >> 6, ln = t & 63, lg = ln >> 4, lc = ln & 15;
  const int gx = gridDim.x, nwg = gridDim.x * gridDim.y;
  int lin = blockIdx.y * gx + blockIdx.x;
  lin = (lin >> 3) + (lin & 7) * (nwg >> 3);
  const int m0 = (lin / gx) * 128, n0 = (lin % gx) * 128;
  const int wr = (w >> 1) * 64, wc = (w & 1) * 64;
  f32x4 acc[4][4] = {};
  const int nkt = (K >> 5) / NSPLIT;
  const int ktb = blockIdx.z * nkt;

  auto stage = [&](int buf, int kt){
    #pragma unroll
    for (int c = 0; c < 2; ++c){
      const int chunk = c*256 + t;
      const int row = chunk >> 2, ke = (chunk & 3) * 8;
      __builtin_amdgcn_global_load_lds(
          (gl_void*)(A + (size_t)(m0+row)*K + (size_t)(ktb+kt)*32 + ke),
          (lds_void*)&As[buf][(c*256 + w*64)*8], 16, 0, 0);
      __builtin_amdgcn_global_load_lds(
          (gl_void*)(BT + (size_t)(n0+row)*K + (size_t)(ktb+kt)*32 + ke),
          (lds_void*)&Bs[buf][(c*256 + w*64)*8], 16, 0, 0);
    }
  };

  stage(0, 0);
  __syncthreads();
  for (int kt = 0; kt < nkt; ++kt){
    const int cur = kt & 1;
    if (kt + 1 < nkt) stage(cur ^ 1, kt + 1);
    bf16x8 af[4], bfr[4];
    #pragma unroll
    for (int i = 0; i < 4; ++i){
      af[i]  = *(const bf16x8*)&As[cur][(wr + i*16 + lc)*32 + lg*8];
      bfr[i] = *(const bf16x8*)&Bs[cur][(wc + i*16 + lc)*32 + lg*8];
    }
    #pragma unroll
    for (int m = 0; m < 4; ++m)
      #pragma unroll
      for (int n = 0; n < 4; ++n)
        acc[m][n] = __builtin_amdgcn_mfma_f32_16x16x32_bf16(af[m], bfr[n], acc[m][n], 0, 0, 0);
    __syncthreads();
  }

  unsigned short* Cp = Cp_base + (size_t)blockIdx.z * (size_t)M * N;
  #pragma unroll
  for (int m = 0; m < 4; ++m)
    #pragma unroll
    for (int n = 0; n < 4; ++n)
      #pragma unroll
      for (int r = 0; r < 4; ++r){
        const int row = m0 + wr + m*16 + lg*4 + r;
        const int col = n0 + wc + n*16 + lc;
        Cp[(size_t)row*N + col] = f2bf(acc[m][n][r]);
      }
}

// ===== GEMM 64x128, BK=32, 2-buf, 4 blocks/CU (24 KB LDS), swizzled ======
// EPI: 0 none, 4 argmin-partials (bias = cbn2).
template<int EPI, bool BIAS, bool RES, bool OUTBF>
__global__ __launch_bounds__(256, 4) void gemm64_bt(
    const unsigned short* __restrict__ A, const unsigned short* __restrict__ BT,
    void* __restrict__ Cv, const float* __restrict__ bias, const float* __restrict__ resid,
    int M, int N, int K)
{
  __shared__ __align__(16) unsigned short As[2][64*32];    // 8 KB
  __shared__ __align__(16) unsigned short Bs[2][128*32];   // 16 KB
  const int t = threadIdx.x;
  const int w = t >> 6, ln = t & 63, lg = ln >> 4, lc = ln & 15;
  const int gx = gridDim.x, nwg = gridDim.x * gridDim.y;
  int lin = blockIdx.y * gx + blockIdx.x;
  lin = (lin >> 3) + (lin & 7) * (nwg >> 3);
  const int bx = lin % gx, by = lin / gx;
  const int m0 = by * 64, n0 = bx * 128;
  const int wr = (w >> 1) * 32, wc = (w & 1) * 64;
  f32x4 acc[2][4] = {};
  const int nkt = K >> 5;

  // 3 loads/thread per tile (A:1, B:2); unit-swizzle (ro>>1)&3 (proven 0-conflict in gemmf)
  auto stage = [&](int buf, int kt){
    {
      const int ro = t >> 2, cu = t & 3;
      const int su = cu ^ ((ro >> 1) & 3);
      __builtin_amdgcn_global_load_lds(
          (gl_void*)(A + (size_t)(m0+ro)*K + (size_t)kt*32 + su*8),
          (lds_void*)&As[buf][(t & ~63)*8], 16, 0, 0);
    }
    #pragma unroll
    for (int j = 0; j < 2; ++j){
      const int u = j*256 + t;
      const int ro = u >> 2, cu = u & 3;
      const int su = cu ^ ((ro >> 1) & 3);
      __builtin_amdgcn_global_load_lds(
          (gl_void*)(BT + (size_t)(n0+ro)*K + (size_t)kt*32 + su*8),
          (lds_void*)&Bs[buf][(j*256 + (t & ~63))*8], 16, 0, 0);
    }
  };

  stage(0, 0);
  __syncthreads();
  for (int kt = 0; kt < nkt; ++kt){
    const int cur = kt & 1;
    if (kt + 1 < nkt) stage(cur ^ 1, kt + 1);
    bf16x8 af[2], bfr[4];
    #pragma unroll
    for (int i = 0; i < 2; ++i){
      const int rowA = wr + i*16 + lc;
      const int cuA = lg ^ ((rowA >> 1) & 3);
      af[i] = *(const bf16x8*)&As[cur][(rowA*4 + cuA)*8];
    }
    #pragma unroll
    for (int i = 0; i < 4; ++i){
      const int rowB = wc + i*16 + lc;
      const int cuB = lg ^ ((rowB >> 1) & 3);
      bfr[i] = *(const bf16x8*)&Bs[cur][(rowB*4 + cuB)*8];
    }
    #pragma unroll
    for (int m = 0; m < 2; ++m)
      #pragma unroll
      for (int n = 0; n < 4; ++n)
        acc[m][n] = __builtin_amdgcn_mfma_f32_16x16x32_bf16(af[m], bfr[n], acc[m][n], 0, 0, 0);
    __syncthreads();
  }

  if constexpr (EPI == 4){
    #pragma unroll
    for (int m = 0; m < 2; ++m){
      #pragma unroll
      for (int r = 0; r < 4; ++r){
        float best = 3.4e38f; int bi = 0;
        #pragma unroll
        for (int n = 0; n < 4; ++n){
          const int col = n0 + wc + n*16 + lc;
          const float d = bias[col] - 2.0f*acc[m][n][r];
          if (d < best){ best = d; bi = col; }
        }
        #pragma unroll
        for (int o = 1; o < 16; o <<= 1){
          const float ob = __shfl_xor(best, o);
          const int oi = __shfl_xor(bi, o);
          if (ob < best || (ob == best && oi < bi)){ best = ob; bi = oi; }
        }
        if (lc == 0){
          const int row = m0 + wr + m*16 + lg*4 + r;
          ((float2*)Cv)[row*16 + bx*2 + (w & 1)] = make_float2(best, (float)bi);
        }
      }
    }
    return;
  }

  #pragma unroll
  for (int m = 0; m < 2; ++m){
    #pragma unroll
    for (int n = 0; n < 4; ++n){
      #pragma unroll
      for (int r = 0; r < 4; ++r){
        const int row = m0 + wr + m*16 + lg*4 + r;
        const int col = n0 + wc + n*16 + lc;
        float v = acc[m][n][r];
        if constexpr (BIAS) v += bias[col];
        if constexpr (RES) v += resid[(size_t)row*N + col];
        if constexpr (OUTBF) ((unsigned short*)Cv)[(size_t)row*N + col] = f2bf(v);
        else                 ((float*)Cv)[(size_t)row*N + col] = v;
      }
    }
  }
}

// ================= Chunkwise retention, C=64 (Tbuf bf16) =================
__global__ __launch_bounds__(256, 2) void chunk_sum(
    const unsigned short* __restrict__ kb, const unsigned short* __restrict__ vb,
    unsigned short* __restrict__ Tbuf)
{
  __shared__ unsigned short KT[64*72];
  __shared__ unsigned short VT[64*72];
  const int t = threadIdx.x, w = t >> 6, ln = t & 63, lg = ln >> 4, lc = ln & 15;
  const int blk = blockIdx.x;          // bh*32 + c
  const int bh = blk >> 5, c = blk & 31;
  const int b = bh >> 4, hh = bh & 15;
  const float lg2g = log2f(1.0f - exp2f(-5.0f - (float)hh));
  #pragma unroll
  for (int ch = 0; ch < 2; ++ch){
    const int chunk = ch*256 + t;
    const int i = chunk >> 3, d0 = (chunk & 7)*8;
    const size_t gofs = ((size_t)(b*2048 + c*64 + i))*1024 + hh*64 + d0;
    const float wi = exp2f(lg2g * (float)(64 - i));
    union {uint4 u; unsigned short s[8];} kv, vv;
    kv.u = *(const uint4*)(kb + gofs);
    vv.u = *(const uint4*)(vb + gofs);
    #pragma unroll
    for (int j = 0; j < 8; ++j){
      KT[(d0+j)*72 + i] = f2bf(bf2f(kv.s[j]) * wi);
      VT[(d0+j)*72 + i] = vv.s[j];
    }
  }
  __syncthreads();
  f32x4 acc[4] = {};
  #pragma unroll
  for (int ks = 0; ks < 2; ++ks){
    const bf16x8 af = *(const bf16x8*)&KT[(w*16 + lc)*72 + ks*32 + lg*8];
    #pragma unroll
    for (int n = 0; n < 4; ++n){
      const bf16x8 bf = *(const bf16x8*)&VT[(n*16 + lc)*72 + ks*32 + lg*8];
      acc[n] = __builtin_amdgcn_mfma_f32_16x16x32_bf16(af, bf, acc[n], 0, 0, 0);
    }
  }
  unsigned short* out = Tbuf + (size_t)blk*4096;
  #pragma unroll
  for (int n = 0; n < 4; ++n)
    #pragma unroll
    for (int r = 0; r < 4; ++r)
      out[(w*16 + lg*4 + r)*64 + n*16 + lc] = f2bf(acc[n][r]);
}

// Phase 2: scan, 128 blocks (bh x 4 quarters of d), bf16 T input
__global__ void chunk_scan(const unsigned short* __restrict__ Tbuf, unsigned short* __restrict__ statesT)
{
  const int bh = blockIdx.x, q = blockIdx.y, t = threadIdx.x;
  const int hh = bh & 15;
  const float gamma = 1.0f - exp2f(-5.0f - (float)hh);
  const float g64 = exp2f(log2f(gamma) * 64.0f);
  float S[4] = {0.f, 0.f, 0.f, 0.f};
  const int dv = t >> 2;                 // 0..63
  const int j0 = q*16 + (t & 3)*4;       // 4 d-elems
  for (int c = 0; c < 32; ++c){
    const size_t base = ((size_t)(bh*32 + c))*4096;
    ushort4 p; p.x = f2bf(S[0]); p.y = f2bf(S[1]); p.z = f2bf(S[2]); p.w = f2bf(S[3]);
    *(ushort4*)(statesT + base + dv*64 + j0) = p;
    #pragma unroll
    for (int j = 0; j < 4; ++j)
      S[j] = g64*S[j] + bf2f(Tbuf[base + (size_t)(j0 + j)*64 + dv]);
  }
}

__global__ __launch_bounds__(256, 2) void retention_chunk(
    const unsigned short* __restrict__ qb, const unsigned short* __restrict__ kb,
    const unsigned short* __restrict__ vb, const unsigned short* __restrict__ gb,
    const unsigned short* __restrict__ statesT, unsigned short* __restrict__ og)
{
  __shared__ unsigned short VT[64*72];
  __shared__ unsigned short Pw[64*72];
  const int t = threadIdx.x, w = t >> 6, ln = t & 63, lg = ln >> 4, lc = ln & 15;
  const int blk = blockIdx.x;          // bh*32 + c
  const int bh = blk >> 5, c = blk & 31;
  const int b = bh >> 4, hh = bh & 15;
  const float lg2g = log2f(1.0f - exp2f(-5.0f - (float)hh));
  float gpr[4];
  #pragma unroll
  for (int r = 0; r < 4; ++r) gpr[r] = exp2f(-lg2g * (float)r);   // gamma^{-r}
  const size_t rowbase = (size_t)(b*2048 + c*64);

  #pragma unroll
  for (int ch = 0; ch < 2; ++ch){
    const int chunk = ch*256 + t;
    const int i = chunk >> 3, d0 = (chunk & 7)*8;
    union {uint4 u; unsigned short s[8];} vv;
    vv.u = *(const uint4*)(vb + (rowbase + i)*1024 + hh*64 + d0);
    #pragma unroll
    for (int j = 0; j < 8; ++j) VT[(d0+j)*72 + i] = vv.s[j];
  }

  bf16x8 Qf[2], Kf[4][2];
  #pragma unroll
  for (int ks = 0; ks < 2; ++ks){
    union {uint4 u; bf16x8 f;} cv;
    cv.u = *(const uint4*)(qb + (rowbase + w*16 + lc)*1024 + hh*64 + ks*32 + lg*8);
    Qf[ks] = cv.f;
    #pragma unroll
    for (int mt = 0; mt < 4; ++mt){
      union {uint4 u; bf16x8 f;} kv;
      kv.u = *(const uint4*)(kb + (rowbase + mt*16 + lc)*1024 + hh*64 + ks*32 + lg*8);
      Kf[mt][ks] = kv.f;
    }
  }

  f32x4 st[4] = {};
  #pragma unroll
  for (int ks = 0; ks < 2; ++ks)
    #pragma unroll
    for (int mt = 0; mt < 4; ++mt)
      st[mt] = __builtin_amdgcn_mfma_f32_16x16x32_bf16(Kf[mt][ks], Qf[ks], st[mt], 0, 0, 0);

  __syncthreads();

  #pragma unroll
  for (int mt = 0; mt < 4; ++mt){
    const int kp = mt*16 + lg*4;
    const int qrow = w*16 + lc;
    const int delta0 = qrow - kp;
    const float dec0 = exp2f(lg2g * (float)delta0) * 0.125f;
    float vals[4];
    #pragma unroll
    for (int r = 0; r < 4; ++r)
      vals[r] = (delta0 >= r) ? st[mt][r] * dec0 * gpr[r] : 0.0f;
    uint2 pk; pk.x = packbf2(vals[0], vals[1]); pk.y = packbf2(vals[2], vals[3]);
    *(uint2*)&Pw[qrow*72 + kp] = pk;
  }

  f32x4 acc[4] = {};
  const unsigned short* Sbase = statesT + (size_t)blk*4096;
  #pragma unroll
  for (int ks = 0; ks < 2; ++ks)
    #pragma unroll
    for (int n = 0; n < 4; ++n){
      union {uint4 u; bf16x8 f;} sv;
      sv.u = *(const uint4*)(Sbase + (n*16 + lc)*64 + ks*32 + lg*8);
      acc[n] = __builtin_amdgcn_mfma_f32_16x16x32_bf16(Qf[ks], sv.f, acc[n], 0, 0, 0);
    }
  #pragma unroll
  for (int n = 0; n < 4; ++n)
    #pragma unroll
    for (int r = 0; r < 4; ++r)
      acc[n][r] *= exp2f(lg2g * (float)(w*16 + lg*4 + r)) * 0.125f;

  #pragma unroll
  for (int ks = 0; ks < 2; ++ks){
    const bf16x8 Pf = *(const bf16x8*)&Pw[(w*16 + lc)*72 + ks*32 + lg*8];
    #pragma unroll
    for (int n = 0; n < 4; ++n){
      const bf16x8 Vf = *(const bf16x8*)&VT[(n*16 + lc)*72 + ks*32 + lg*8];
      acc[n] = __builtin_amdgcn_mfma_f32_16x16x32_bf16(Pf, Vf, acc[n], 0, 0, 0);
    }
  }

  #pragma unroll
  for (int n = 0; n < 4; ++n){
    #pragma unroll
    for (int r = 0; r < 4; ++r){
      const size_t row = rowbase + w*16 + lg*4 + r;
      const int col = hh*64 + n*16 + lc;
      const float gv = bf2f(gb[row*1024 + col]);
      og[row*1024 + col] = f2bf(acc[n][r] * gv);
    }
  }
}

// ===== RVQ bf16 chain: argmin-from-partials + in-place residual update =====
// FINAL emits out = x2 + xn - nr  (x2, xn bf16)
template<int FINAL>
__global__ void rvq_update4(const unsigned short* __restrict__ cbbf_l,
                            const float2* __restrict__ partials,
                            unsigned short* __restrict__ resb, float* __restrict__ qlpart, int lvl,
                            const unsigned short* __restrict__ x2, const unsigned short* __restrict__ xn,
                            float* __restrict__ outf)
{
  const int m = blockIdx.x, t = threadIdx.x;
  __shared__ int sid;
  if (t == 0){
    float best = 3.4e38f; int bi = 0;
    #pragma unroll
    for (int p = 0; p < 16; ++p){
      const float2 pr = partials[m*16 + p];
      if (pr.x < best){ best = pr.x; bi = (int)pr.y; }
    }
    sid = bi;
  }
  __syncthreads();
  const int id = sid;
  const ushort4 qv = ((const ushort4*)(cbbf_l + (size_t)id*1024))[t];
  const ushort4 rv = ((const ushort4*)(resb + (size_t)m*1024))[t];
  const float n0 = bf2f(rv.x) - bf2f(qv.x);
  const float n1 = bf2f(rv.y) - bf2f(qv.y);
  const float n2 = bf2f(rv.z) - bf2f(qv.z);
  const float n3 = bf2f(rv.w) - bf2f(qv.w);
  if constexpr (FINAL){
    const size_t off = (size_t)m*256 + t;
    const ushort4 a = ((const ushort4*)x2)[off];
    const ushort4 b = ((const ushort4*)xn)[off];
    float4 o;
    o.x = bf2f(a.x) + bf2f(b.x) - n0;
    o.y = bf2f(a.y) + bf2f(b.y) - n1;
    o.z = bf2f(a.z) + bf2f(b.z) - n2;
    o.w = bf2f(a.w) + bf2f(b.w) - n3;
    ((float4*)outf)[off] = o;
  } else {
    ushort4 nb; nb.x = f2bf(n0); nb.y = f2bf(n1); nb.z = f2bf(n2); nb.w = f2bf(n3);
    ((ushort4*)(resb + (size_t)m*1024))[t] = nb;
  }
  float s = n0*n0 + n1*n1 + n2*n2 + n3*n3;
  #pragma unroll
  for (int o = 32; o >= 1; o >>= 1) s += __shfl_down(s, o);
  __shared__ float red[4];
  if ((t & 63) == 0) red[t >> 6] = s;
  __syncthreads();
  if (t == 0) qlpart[lvl*4096 + m] = red[0]+red[1]+red[2]+red[3];
}

__global__ void ql_final(const float* __restrict__ qlpart, float* __restrict__ outs)
{
  const int t = threadIdx.x;                     // 1024 threads
  float s = 0.f;
  for (int i = t; i < 16384; i += 1024) s += qlpart[i];
  #pragma unroll
  for (int o = 32; o >= 1; o >>= 1) s += __shfl_down(s, o);
  __shared__ float red[16];
  if ((t & 63) == 0) red[t >> 6] = s;
  __syncthreads();
  if (t == 0){
    float q = 0.f;
    #pragma unroll
    for (int i = 0; i < 16; ++i) q += red[i];
    q *= (1.0f/4194304.0f) * 0.25f;
    outs[0] = q; outs[1] = q;
  }
}

// ================= launcher =================
extern "C" void kernel_launch(void* const* d_in, const int* in_sizes, int n_in,
                              void* d_out, int out_size, void* d_ws, size_t ws_size,
                              hipStream_t stream)
{
  const float* x     = (const float*)d_in[0];
  const float* ln1_g = (const float*)d_in[1];
  const float* ln1_b = (const float*)d_in[2];
  const float* wq    = (const float*)d_in[3];
  const float* wk    = (const float*)d_in[4];
  const float* wv    = (const float*)d_in[5];
  const float* wg    = (const float*)d_in[6];
  const float* wo    = (const float*)d_in[7];
  const float* ln2_g = (const float*)d_in[8];
  const float* ln2_b = (const float*)d_in[9];
  const float* w1    = (const float*)d_in[10];
  const float* b1    = (const float*)d_in[11];
  const float* w2    = (const float*)d_in[12];
  const float* b2    = (const float*)d_in[13];
  const float* ln3_g = (const float*)d_in[14];
  const float* ln3_b = (const float*)d_in[15];
  const float* cb    = (const float*)d_in[16];

  char* ws = (char*)d_ws;
  const size_t MB = 1024*1024;
  unsigned short* wqkvgT = (unsigned short*)(ws + 0*MB);
  unsigned short* w1T  = (unsigned short*)(ws + 10*MB);
  unsigned short* w2T  = (unsigned short*)(ws + 18*MB);
  unsigned short* cbbf = (unsigned short*)(ws + 26*MB);
  float* cbn2     = (float*)(ws + 34*MB);
  float* qlpart   = (float*)(ws + 34*MB + 16*1024);
  float2* partials= (float2*)(ws + 34*MB + 128*1024);
  unsigned short* hbf  = (unsigned short*)(ws + 35*MB);
  unsigned short* qbuf = (unsigned short*)(ws + 43*MB);
  unsigned short* kbuf = (unsigned short*)(ws + 51*MB);
  unsigned short* vbuf = (unsigned short*)(ws + 59*MB);
  unsigned short* gbuf = (unsigned short*)(ws + 67*MB);
  unsigned short* skbuf = (unsigned short*)(ws + 43*MB);   // bf16 split-K partials x4 (32MB, reuses q/k/v/g)
  unsigned short* ogb  = (unsigned short*)(ws + 75*MB);
  unsigned short* x1b  = (unsigned short*)(ws + 83*MB);    // bf16 residual stream
  unsigned short* h2   = (unsigned short*)(ws + 99*MB);
  unsigned short* a1   = (unsigned short*)(ws + 107*MB);
  unsigned short* Tbuf = (unsigned short*)(ws + 139*MB);   // bf16, dead by MLP
  unsigned short* x2b  = (unsigned short*)(ws + 147*MB);   // bf16
  unsigned short* statesT = (unsigned short*)(ws + 155*MB);// dead by ln3 time
  unsigned short* xnb  = (unsigned short*)(ws + 163*MB);   // bf16 pristine xn
  unsigned short* resb = (unsigned short*)(ws + 171*MB);
  float2* rtab  = (float2*)(ws + 179*MB);

  float* outf = (float*)d_out;

  // --- fused weight prep + ln1 ---
  Ptr5 p5; p5.p[0]=wq; p5.p[1]=wk; p5.p[2]=wv; p5.p[3]=wg; p5.p[4]=wo;
  hipLaunchKernelGGL(prep_all, dim3(21760), dim3(256), 0, stream,
                     p5, wqkvgT, w1, w1T, w2, w2T, cb, cbbf, cbn2, rtab,
                     x, ln1_g, ln1_b, hbf);

  // --- retention sub-block ---
  hipLaunchKernelGGL((gemmf<3>), dim3(16,32), dim3(512), 0, stream,
                     hbf, wqkvgT, qbuf, (const float*)nullptr, (const float2*)rtab, 4096, 4096, 1024);
  hipLaunchKernelGGL(chunk_sum,  dim3(1024), dim3(256), 0, stream, kbuf, vbuf, Tbuf);
  hipLaunchKernelGGL(chunk_scan, dim3(32,4), dim3(256), 0, stream, Tbuf, statesT);
  hipLaunchKernelGGL(retention_chunk, dim3(1024), dim3(256), 0, stream,
                     qbuf, kbuf, vbuf, gbuf, statesT, ogb);
  hipLaunchKernelGGL((gemm64_bt<0,false,true,true>), dim3(8,64), dim3(256), 0, stream,
                     ogb, wqkvgT + 4194304, (void*)x1b, (const float*)nullptr, x, 4096, 1024, 1024);

  // --- MLP sub-block ---
  hipLaunchKernelGGL(ln_bf, dim3(4096), dim3(256), 0, stream, x1b, ln2_g, ln2_b, h2);
  hipLaunchKernelGGL((gemmf<2>), dim3(16,32), dim3(512), 0, stream,
                     h2, w1T, a1, b1, (const float2*)rtab, 4096, 4096, 1024);
  hipLaunchKernelGGL((gemm128_sk<4>), dim3(8,32,4), dim3(256), 0, stream,
                     a1, w2T, skbuf, 4096, 1024, 4096);
  hipLaunchKernelGGL(reduce_ln, dim3(4096), dim3(256), 0, stream,
                     skbuf, b2, x1b, x2b, ln3_g, ln3_b, resb, xnb);

  // --- RVQ (bf16 chain) ---
  for (int lvl = 0; lvl < 4; ++lvl){
    hipLaunchKernelGGL((gemm64_bt<4,false,false,false>), dim3(8,64), dim3(256), 0, stream,
                       resb, cbbf + (size_t)lvl*1048576, (void*)partials,
                       cbn2 + lvl*1024, (const float*)nullptr, 4096, 1024, 1024);
    if (lvl < 3)
      hipLaunchKernelGGL((rvq_update4<0>), dim3(4096), dim3(256), 0, stream,
                         cbbf + (size_t)lvl*1048576, partials, resb, qlpart, lvl,
                         (const unsigned short*)nullptr, (const unsigned short*)nullptr, (float*)nullptr);
    else
      hipLaunchKernelGGL((rvq_update4<1>), dim3(4096), dim3(256), 0, stream,
                         cbbf + (size_t)lvl*1048576, partials, resb, qlpart, lvl,
                         x2b, xnb, outf);
  }

  // --- outputs ---
  hipLaunchKernelGGL(ql_final, dim3(1), dim3(1024), 0, stream, qlpart, outf + 4194304);
}

// Round 19
// 359.794 us; speedup vs baseline: 1.0245x; 1.0245x over previous
//
#include <hip/hip_runtime.h>
#include <cstdint>
#include <cstddef>

#define DEV __device__ __forceinline__

typedef __attribute__((ext_vector_type(8))) short bf16x8;
typedef __attribute__((ext_vector_type(4))) float f32x4;

typedef const __attribute__((address_space(1))) void gl_void;
typedef __attribute__((address_space(3))) void lds_void;

// ---------- small helpers ----------
DEV unsigned short f2bf(float f){
  union { float f; uint32_t u; } v; v.f = f;
  uint32_t r = v.u + 0x7FFFu + ((v.u >> 16) & 1u);  // RNE
  return (unsigned short)(r >> 16);
}
DEV float bf2f(unsigned short u){
  union { uint32_t u; float f; } v; v.u = ((uint32_t)u) << 16; return v.f;
}
DEV uint32_t packbf2(float a, float b){
  return (uint32_t)f2bf(a) | ((uint32_t)f2bf(b) << 16);
}

// ================= LayerNorm (bf16 in -> bf16 out) =================
__global__ void ln_bf(const unsigned short* __restrict__ x, const float* __restrict__ gw,
                      const float* __restrict__ bw, unsigned short* __restrict__ obf)
{
  const int row = blockIdx.x, t = threadIdx.x;
  const ushort4 xv = ((const ushort4*)(x + (size_t)row*1024))[t];
  float4 v; v.x = bf2f(xv.x); v.y = bf2f(xv.y); v.z = bf2f(xv.z); v.w = bf2f(xv.w);
  float s  = v.x + v.y + v.z + v.w;
  float s2 = v.x*v.x + v.y*v.y + v.z*v.z + v.w*v.w;
  #pragma unroll
  for (int o = 32; o >= 1; o >>= 1){ s += __shfl_down(s, o); s2 += __shfl_down(s2, o); }
  __shared__ float red[8];
  const int w = t >> 6, ln = t & 63;
  if (ln == 0){ red[w] = s; red[4+w] = s2; }
  __syncthreads();
  const float fs  = red[0]+red[1]+red[2]+red[3];
  const float fs2 = red[4]+red[5]+red[6]+red[7];
  const float mean = fs * (1.0f/1024.0f);
  const float var  = fs2 * (1.0f/1024.0f) - mean*mean;
  const float rstd = rsqrtf(var + 1e-5f);
  const float4 gv = ((const float4*)gw)[t];
  const float4 bv = ((const float4*)bw)[t];
  ushort4 ob;
  ob.x = f2bf((v.x-mean)*rstd*gv.x + bv.x);
  ob.y = f2bf((v.y-mean)*rstd*gv.y + bv.y);
  ob.z = f2bf((v.z-mean)*rstd*gv.z + bv.z);
  ob.w = f2bf((v.w-mean)*rstd*gv.w + bv.w);
  ((ushort4*)(obf + (size_t)row*1024))[t] = ob;
}

// ===== fused: split-K reduce (x2 = p0..p3 + x1 + b2; bf16 in/out) + LN3 =====
__global__ void reduce_ln(const unsigned short* __restrict__ p, const float* __restrict__ b2,
                          const unsigned short* __restrict__ x1, unsigned short* __restrict__ x2,
                          const float* __restrict__ g3, const float* __restrict__ b3,
                          unsigned short* __restrict__ resb, unsigned short* __restrict__ xnb)
{
  const int row = blockIdx.x, t = threadIdx.x;
  const size_t off = (size_t)row*1024/4 + t;
  const ushort4 rv = ((const ushort4*)x1)[off];
  const float4 bv2 = ((const float4*)b2)[t];
  float4 v;
  v.x = bf2f(rv.x) + bv2.x; v.y = bf2f(rv.y) + bv2.y;
  v.z = bf2f(rv.z) + bv2.z; v.w = bf2f(rv.w) + bv2.w;
  #pragma unroll
  for (int pl = 0; pl < 4; ++pl){
    const ushort4 a = ((const ushort4*)(p + (size_t)pl*4194304))[off];
    v.x += bf2f(a.x); v.y += bf2f(a.y); v.z += bf2f(a.z); v.w += bf2f(a.w);
  }
  ushort4 xo; xo.x = f2bf(v.x); xo.y = f2bf(v.y); xo.z = f2bf(v.z); xo.w = f2bf(v.w);
  ((ushort4*)x2)[off] = xo;
  float s  = v.x + v.y + v.z + v.w;
  float s2 = v.x*v.x + v.y*v.y + v.z*v.z + v.w*v.w;
  #pragma unroll
  for (int o = 32; o >= 1; o >>= 1){ s += __shfl_down(s, o); s2 += __shfl_down(s2, o); }
  __shared__ float red[8];
  const int w = t >> 6, ln = t & 63;
  if (ln == 0){ red[w] = s; red[4+w] = s2; }
  __syncthreads();
  const float fs  = red[0]+red[1]+red[2]+red[3];
  const float fs2 = red[4]+red[5]+red[6]+red[7];
  const float mean = fs * (1.0f/1024.0f);
  const float var  = fs2 * (1.0f/1024.0f) - mean*mean;
  const float rstd = rsqrtf(var + 1e-5f);
  const float4 gv = ((const float4*)g3)[t];
  const float4 bv = ((const float4*)b3)[t];
  ushort4 ob;
  ob.x = f2bf((v.x-mean)*rstd*gv.x + bv.x);
  ob.y = f2bf((v.y-mean)*rstd*gv.y + bv.y);
  ob.z = f2bf((v.z-mean)*rstd*gv.z + bv.z);
  ob.w = f2bf((v.w-mean)*rstd*gv.w + bv.w);
  ((ushort4*)resb)[off] = ob;
  ((ushort4*)xnb)[off] = ob;
}

// ================= fused weight prep + ln1 ==========
struct Ptr5 { const float* p[5]; };

DEV void dev_transpose(const float* __restrict__ src, unsigned short* __restrict__ dst,
                       int r0, int c0, int R, int C)
{
  __shared__ float tile[32][33];
  const int tx = threadIdx.x & 31, ty = threadIdx.x >> 5;   // 32 x 8
  #pragma unroll
  for (int i = 0; i < 32; i += 8)
    tile[ty+i][tx] = src[(size_t)(r0+ty+i)*C + c0 + tx];
  __syncthreads();
  #pragma unroll
  for (int i = 0; i < 32; i += 8)
    dst[(size_t)(c0+ty+i)*R + r0 + tx] = f2bf(tile[tx][ty+i]);
}

__global__ void prep_all(Ptr5 p5, unsigned short* __restrict__ wqkvgT,
                         const float* __restrict__ w1, unsigned short* __restrict__ w1T,
                         const float* __restrict__ w2, unsigned short* __restrict__ w2T,
                         const float* __restrict__ cb, unsigned short* __restrict__ cbbf,
                         float* __restrict__ cbn2, float2* __restrict__ rtab,
                         const float* __restrict__ x, const float* __restrict__ ln1_g,
                         const float* __restrict__ ln1_b, unsigned short* __restrict__ hbf)
{
  const int b = blockIdx.x, t = threadIdx.x;
  if (b < 5120){                                  // 5x 1024x1024 transpose
    const int z = b >> 10, r = b & 1023;
    dev_transpose(p5.p[z], wqkvgT + (size_t)z*1048576, (r >> 5)*32, (r & 31)*32, 1024, 1024);
  } else if (b < 9216){                           // w1 [1024][4096] -> w1T [4096][1024]
    const int r = b - 5120;
    dev_transpose(w1, w1T, (r >> 7)*32, (r & 127)*32, 1024, 4096);
  } else if (b < 13312){                          // w2 [4096][1024] -> w2T [1024][4096]
    const int r = b - 9216;
    dev_transpose(w2, w2T, (r >> 5)*32, (r & 31)*32, 4096, 1024);
  } else if (b < 17408){                          // codebook cast + norms
    const int code = b - 13312;
    const float4 v = ((const float4*)(cb + (size_t)code*1024))[t];
    ushort4 o; o.x = f2bf(v.x); o.y = f2bf(v.y); o.z = f2bf(v.z); o.w = f2bf(v.w);
    ((ushort4*)(cbbf + (size_t)code*1024))[t] = o;
    float s = v.x*v.x + v.y*v.y + v.z*v.z + v.w*v.w;
    #pragma unroll
    for (int off = 32; off >= 1; off >>= 1) s += __shfl_down(s, off);
    __shared__ float red[4];
    if ((t & 63) == 0) red[t >> 6] = s;
    __syncthreads();
    if (t == 0) cbn2[code] = red[0]+red[1]+red[2]+red[3];
  } else if (b < 17664){                          // rope table
    const int i = (b - 17408)*256 + t;            // 65536 = 2048 x 32
    const int s = i >> 5, j = i & 31;
    const float ang = (float)s * exp2f(-(float)j * 0.4152410118609203f);
    float sn, cs; sincosf(ang, &sn, &cs);
    rtab[i] = make_float2(cs, sn);
  } else {                                        // ln1
    const int row = b - 17664;
    const float4 v = ((const float4*)(x + (size_t)row*1024))[t];
    float s  = v.x + v.y + v.z + v.w;
    float s2 = v.x*v.x + v.y*v.y + v.z*v.z + v.w*v.w;
    #pragma unroll
    for (int o = 32; o >= 1; o >>= 1){ s += __shfl_down(s, o); s2 += __shfl_down(s2, o); }
    __shared__ float red2[8];
    const int w = t >> 6, ln = t & 63;
    if (ln == 0){ red2[w] = s; red2[4+w] = s2; }
    __syncthreads();
    const float fs  = red2[0]+red2[1]+red2[2]+red2[3];
    const float fs2 = red2[4]+red2[5]+red2[6]+red2[7];
    const float mean = fs * (1.0f/1024.0f);
    const float var  = fs2 * (1.0f/1024.0f) - mean*mean;
    const float rstd = rsqrtf(var + 1e-5f);
    const float4 gv = ((const float4*)ln1_g)[t];
    const float4 bv = ((const float4*)ln1_b)[t];
    ushort4 ob;
    ob.x = f2bf((v.x-mean)*rstd*gv.x + bv.x);
    ob.y = f2bf((v.y-mean)*rstd*gv.y + bv.y);
    ob.z = f2bf((v.z-mean)*rstd*gv.z + bv.z);
    ob.w = f2bf((v.w-mean)*rstd*gv.w + bv.w);
    ((ushort4*)(hbf + (size_t)row*1024))[t] = ob;
  }
}

// ===== GEMM 128x256, BK=32, 3-buf counted-vmcnt, 2 blocks/CU (72 KB LDS), 8 waves ======
// EPI: 2 = gelu+bias (bf16 out, C[M][N]); 3 = QKVG split (rope table on sects 0,1; silu on 3)
template<int EPI>
__global__ __launch_bounds__(512, 2) void gemmf(
    const unsigned short* __restrict__ A, const unsigned short* __restrict__ BT,
    unsigned short* __restrict__ C, const float* __restrict__ bias,
    const float2* __restrict__ rt, int M, int N, int K)
{
  __shared__ __align__(16) unsigned short SH[36864];
  const int t = threadIdx.x;
  const int w = t >> 6, ln = t & 63, lg = ln >> 4, lc = ln & 15;
  const int wm = w >> 2, wn = w & 3;            // 2 x 4 wave grid: 64 rows x 64 cols per wave
  const int gx = gridDim.x, nwg = gridDim.x * gridDim.y;
  int lin = blockIdx.y * gx + blockIdx.x;
  lin = (lin >> 3) + (lin & 7) * (nwg >> 3);    // chunked XCD swizzle (nwg % 8 == 0)
  const int m0 = (lin / gx) * 128, n0 = (lin % gx) * 256;
  const int nkt = K >> 5;

  f32x4 acc[4][4] = {};
  bf16x8 aF[4], bF[4];

  auto stage = [&](int buf, int kt){
    const int ub = buf*1536;
    {
      const int ro = t >> 2, cu = t & 3;
      const int su = cu ^ ((ro >> 1) & 3);
      __builtin_amdgcn_global_load_lds(
        (gl_void*)(A + (size_t)(m0+ro)*K + (size_t)kt*32 + su*8),
        (lds_void*)&SH[(ub + (t & ~63))*8], 16, 0, 0);
    }
    #pragma unroll
    for (int j = 0; j < 2; ++j){
      const int u = j*512 + t;
      const int ro = u >> 2, cu = u & 3;
      const int su = cu ^ ((ro >> 1) & 3);
      __builtin_amdgcn_global_load_lds(
        (gl_void*)(BT + (size_t)(n0+ro)*K + (size_t)kt*32 + su*8),
        (lds_void*)&SH[(ub + 512 + j*512 + (t & ~63))*8], 16, 0, 0);
    }
  };

  auto ldA = [&](int buf, int mf) -> bf16x8 {
    const int R = wm*64 + mf*16 + lc;
    const int cu = lg ^ ((R >> 1) & 3);
    return *(const bf16x8*)&SH[(buf*1536 + R*4 + cu)*8];
  };
  auto ldB = [&](int buf, int nf) -> bf16x8 {
    const int R = wn*64 + nf*16 + lc;
    const int cu = lg ^ ((R >> 1) & 3);
    return *(const bf16x8*)&SH[(buf*1536 + 512 + R*4 + cu)*8];
  };

  stage(0, 0); stage(1, 1);
  asm volatile("s_waitcnt vmcnt(3)" ::: "memory");
  __builtin_amdgcn_s_barrier();

  for (int kt = 0; kt < nkt; ++kt){
    const int cur = kt % 3;
    const bool pf = (kt + 2 < nkt);

    if (pf) stage((kt + 2) % 3, kt + 2);
    #pragma unroll
    for (int f = 0; f < 4; ++f) aF[f] = ldA(cur, f);
    bF[0] = ldB(cur, 0); bF[1] = ldB(cur, 1);
    __builtin_amdgcn_s_barrier();
    __builtin_amdgcn_s_setprio(1);
    #pragma unroll
    for (int mf = 0; mf < 4; ++mf)
      #pragma unroll
      for (int nf = 0; nf < 2; ++nf)
        acc[mf][nf] = __builtin_amdgcn_mfma_f32_16x16x32_bf16(aF[mf], bF[nf], acc[mf][nf], 0, 0, 0);
    __builtin_amdgcn_s_setprio(0);
    asm volatile("s_waitcnt lgkmcnt(0)" ::: "memory");
    __builtin_amdgcn_s_barrier();

    bF[2] = ldB(cur, 2); bF[3] = ldB(cur, 3);
    __builtin_amdgcn_s_barrier();
    __builtin_amdgcn_s_setprio(1);
    #pragma unroll
    for (int mf = 0; mf < 4; ++mf)
      #pragma unroll
      for (int nf = 2; nf < 4; ++nf)
        acc[mf][nf] = __builtin_amdgcn_mfma_f32_16x16x32_bf16(aF[mf], bF[nf], acc[mf][nf], 0, 0, 0);
    __builtin_amdgcn_s_setprio(0);
    asm volatile("s_waitcnt lgkmcnt(0)" ::: "memory");
    if (pf) asm volatile("s_waitcnt vmcnt(3)" ::: "memory");
    else    asm volatile("s_waitcnt vmcnt(0)" ::: "memory");
    __builtin_amdgcn_s_barrier();
  }

  if constexpr (EPI == 3){
    const int sect = n0 >> 10;
    unsigned short* outp = C + (size_t)sect*4194304;
    const int cb1 = n0 & 1023;
    #pragma unroll
    for (int mf = 0; mf < 4; ++mf){
      #pragma unroll
      for (int r = 0; r < 4; ++r){
        const int row = m0 + wm*64 + mf*16 + lg*4 + r;
        const int s_ = row & 2047;
        #pragma unroll
        for (int nf = 0; nf < 4; ++nf){
          const int c1 = cb1 + wn*64 + nf*16 + lc;
          float v = acc[mf][nf][r];
          if (sect <= 1){
            const float2 cs = rt[(s_ << 5) + (c1 & 31)];
            const float vp = acc[mf][nf ^ 2][r];
            v = (c1 & 32) ? (v*cs.x + vp*cs.y) : (v*cs.x - vp*cs.y);
          } else if (sect == 3){
            v = v * (1.0f / (1.0f + __expf(-v)));
          }
          outp[(size_t)row*1024 + c1] = f2bf(v);
        }
      }
    }
  } else {
    #pragma unroll
    for (int mf = 0; mf < 4; ++mf){
      #pragma unroll
      for (int r = 0; r < 4; ++r){
        const int row = m0 + wm*64 + mf*16 + lg*4 + r;
        #pragma unroll
        for (int nf = 0; nf < 4; ++nf){
          const int col = n0 + wn*64 + nf*16 + lc;
          float v = acc[mf][nf][r] + bias[col];
          v = 0.5f * v * (1.0f + erff(v * 0.70710678118654752f));
          C[(size_t)row*N + col] = f2bf(v);
        }
      }
    }
  }
}

// ===== GEMM 128x128, BK=32, m97-exact, 4 blocks/CU, split-K (bf16 partial out) =====
template<int NSPLIT>
__global__ __launch_bounds__(256, 4) void gemm128_sk(
    const unsigned short* __restrict__ A, const unsigned short* __restrict__ BT,
    unsigned short* __restrict__ Cp_base, int M, int N, int K)
{
  __shared__ __align__(16) unsigned short As[2][128*32];
  __shared__ __align__(16) unsigned short Bs[2][128*32];
  const int t = threadIdx.x;
  const int w = t >> 6, ln = t & 63, lg = ln >> 4, lc = ln & 15;
  const int gx = gridDim.x, nwg = gridDim.x * gridDim.y;
  int lin = blockIdx.y * gx + blockIdx.x;
  lin = (lin >> 3) + (lin & 7) * (nwg >> 3);
  const int m0 = (lin / gx) * 128, n0 = (lin % gx) * 128;
  const int wr = (w >> 1) * 64, wc = (w & 1) * 64;
  f32x4 acc[4][4] = {};
  const int nkt = (K >> 5) / NSPLIT;
  const int ktb = blockIdx.z * nkt;

  auto stage = [&](int buf, int kt){
    #pragma unroll
    for (int c = 0; c < 2; ++c){
      const int chunk = c*256 + t;
      const int row = chunk >> 2, ke = (chunk & 3) * 8;
      __builtin_amdgcn_global_load_lds(
          (gl_void*)(A + (size_t)(m0+row)*K + (size_t)(ktb+kt)*32 + ke),
          (lds_void*)&As[buf][(c*256 + w*64)*8], 16, 0, 0);
      __builtin_amdgcn_global_load_lds(
          (gl_void*)(BT + (size_t)(n0+row)*K + (size_t)(ktb+kt)*32 + ke),
          (lds_void*)&Bs[buf][(c*256 + w*64)*8], 16, 0, 0);
    }
  };

  stage(0, 0);
  __syncthreads();
  for (int kt = 0; kt < nkt; ++kt){
    const int cur = kt & 1;
    if (kt + 1 < nkt) stage(cur ^ 1, kt + 1);
    bf16x8 af[4], bfr[4];
    #pragma unroll
    for (int i = 0; i < 4; ++i){
      af[i]  = *(const bf16x8*)&As[cur][(wr + i*16 + lc)*32 + lg*8];
      bfr[i] = *(const bf16x8*)&Bs[cur][(wc + i*16 + lc)*32 + lg*8];
    }
    #pragma unroll
    for (int m = 0; m < 4; ++m)
      #pragma unroll
      for (int n = 0; n < 4; ++n)
        acc[m][n] = __builtin_amdgcn_mfma_f32_16x16x32_bf16(af[m], bfr[n], acc[m][n], 0, 0, 0);
    __syncthreads();
  }

  unsigned short* Cp = Cp_base + (size_t)blockIdx.z * (size_t)M * N;
  #pragma unroll
  for (int m = 0; m < 4; ++m)
    #pragma unroll
    for (int n = 0; n < 4; ++n)
      #pragma unroll
      for (int r = 0; r < 4; ++r){
        const int row = m0 + wr + m*16 + lg*4 + r;
        const int col = n0 + wc + n*16 + lc;
        Cp[(size_t)row*N + col] = f2bf(acc[m][n][r]);
      }
}

// ===== GEMM 64x128, BK=64, 2-buf, 3 blocks/CU =====
// EPI: 0 none, 4 argmin-partials (bias = cbn2).
template<int EPI, bool BIAS, bool RES, bool OUTBF>
__global__ __launch_bounds__(256, 3) void gemm64_bt(
    const unsigned short* __restrict__ A, const unsigned short* __restrict__ BT,
    void* __restrict__ Cv, const float* __restrict__ bias, const float* __restrict__ resid,
    int M, int N, int K)
{
  __shared__ __align__(16) unsigned short As[2][64*64];
  __shared__ __align__(16) unsigned short Bs[2][128*64];
  const int t = threadIdx.x;
  const int w = t >> 6, ln = t & 63, lg = ln >> 4, lc = ln & 15;
  const int gx = gridDim.x, nwg = gridDim.x * gridDim.y;
  int lin = blockIdx.y * gx + blockIdx.x;
  lin = (lin >> 3) + (lin & 7) * (nwg >> 3);
  const int bx = lin % gx, by = lin / gx;
  const int m0 = by * 64, n0 = bx * 128;
  const int wr = (w >> 1) * 32, wc = (w & 1) * 64;
  f32x4 acc[2][4] = {};
  const int nkt = K >> 6;

  auto stage = [&](int buf, int kt){
    #pragma unroll
    for (int c = 0; c < 2; ++c){
      const int chunk = c*256 + t;
      const int row = chunk >> 3;
      const int kb = (((chunk & 7) << 4) ^ ((row & 7) << 4)) >> 1;
      __builtin_amdgcn_global_load_lds(
          (gl_void*)(A + (size_t)(m0+row)*K + (size_t)kt*64 + kb),
          (lds_void*)&As[buf][(c*256 + w*64)*8], 16, 0, 0);
    }
    #pragma unroll
    for (int c = 0; c < 4; ++c){
      const int chunk = c*256 + t;
      const int row = chunk >> 3;
      const int kb = (((chunk & 7) << 4) ^ ((row & 7) << 4)) >> 1;
      __builtin_amdgcn_global_load_lds(
          (gl_void*)(BT + (size_t)(n0+row)*K + (size_t)kt*64 + kb),
          (lds_void*)&Bs[buf][(c*256 + w*64)*8], 16, 0, 0);
    }
  };

  stage(0, 0);
  __syncthreads();
  for (int kt = 0; kt < nkt; ++kt){
    const int cur = kt & 1;
    if (kt + 1 < nkt) stage(cur ^ 1, kt + 1);
    #pragma unroll
    for (int ks = 0; ks < 2; ++ks){
      bf16x8 af[2], bfr[4];
      #pragma unroll
      for (int i = 0; i < 2; ++i){
        const int rowA = wr + i*16 + lc;
        const int colA = (((ks<<6) + (lg<<4)) ^ ((rowA & 7) << 4)) >> 1;
        af[i] = *(const bf16x8*)&As[cur][rowA*64 + colA];
      }
      #pragma unroll
      for (int i = 0; i < 4; ++i){
        const int rowB = wc + i*16 + lc;
        const int colB = (((ks<<6) + (lg<<4)) ^ ((rowB & 7) << 4)) >> 1;
        bfr[i] = *(const bf16x8*)&Bs[cur][rowB*64 + colB];
      }
      #pragma unroll
      for (int m = 0; m < 2; ++m)
        #pragma unroll
        for (int n = 0; n < 4; ++n)
          acc[m][n] = __builtin_amdgcn_mfma_f32_16x16x32_bf16(af[m], bfr[n], acc[m][n], 0, 0, 0);
    }
    __syncthreads();
  }

  if constexpr (EPI == 4){
    #pragma unroll
    for (int m = 0; m < 2; ++m){
      #pragma unroll
      for (int r = 0; r < 4; ++r){
        float best = 3.4e38f; int bi = 0;
        #pragma unroll
        for (int n = 0; n < 4; ++n){
          const int col = n0 + wc + n*16 + lc;
          const float d = bias[col] - 2.0f*acc[m][n][r];
          if (d < best){ best = d; bi = col; }
        }
        #pragma unroll
        for (int o = 1; o < 16; o <<= 1){
          const float ob = __shfl_xor(best, o);
          const int oi = __shfl_xor(bi, o);
          if (ob < best || (ob == best && oi < bi)){ best = ob; bi = oi; }
        }
        if (lc == 0){
          const int row = m0 + wr + m*16 + lg*4 + r;
          ((float2*)Cv)[row*16 + bx*2 + (w & 1)] = make_float2(best, (float)bi);
        }
      }
    }
    return;
  }

  #pragma unroll
  for (int m = 0; m < 2; ++m){
    #pragma unroll
    for (int n = 0; n < 4; ++n){
      #pragma unroll
      for (int r = 0; r < 4; ++r){
        const int row = m0 + wr + m*16 + lg*4 + r;
        const int col = n0 + wc + n*16 + lc;
        float v = acc[m][n][r];
        if constexpr (BIAS) v += bias[col];
        if constexpr (RES) v += resid[(size_t)row*N + col];
        if constexpr (OUTBF) ((unsigned short*)Cv)[(size_t)row*N + col] = f2bf(v);
        else                 ((float*)Cv)[(size_t)row*N + col] = v;
      }
    }
  }
}

// ================= Chunkwise retention, C=64 (Tbuf bf16) =================
__global__ __launch_bounds__(256, 2) void chunk_sum(
    const unsigned short* __restrict__ kb, const unsigned short* __restrict__ vb,
    unsigned short* __restrict__ Tbuf)
{
  __shared__ unsigned short KT[64*72];
  __shared__ unsigned short VT[64*72];
  const int t = threadIdx.x, w = t >> 6, ln = t & 63, lg = ln >> 4, lc = ln & 15;
  const int blk = blockIdx.x;          // bh*32 + c
  const int bh = blk >> 5, c = blk & 31;
  const int b = bh >> 4, hh = bh & 15;
  const float lg2g = log2f(1.0f - exp2f(-5.0f - (float)hh));
  #pragma unroll
  for (int ch = 0; ch < 2; ++ch){
    const int chunk = ch*256 + t;
    const int i = chunk >> 3, d0 = (chunk & 7)*8;
    const size_t gofs = ((size_t)(b*2048 + c*64 + i))*1024 + hh*64 + d0;
    const float wi = exp2f(lg2g * (float)(64 - i));
    union {uint4 u; unsigned short s[8];} kv, vv;
    kv.u = *(const uint4*)(kb + gofs);
    vv.u = *(const uint4*)(vb + gofs);
    #pragma unroll
    for (int j = 0; j < 8; ++j){
      KT[(d0+j)*72 + i] = f2bf(bf2f(kv.s[j]) * wi);
      VT[(d0+j)*72 + i] = vv.s[j];
    }
  }
  __syncthreads();
  f32x4 acc[4] = {};
  #pragma unroll
  for (int ks = 0; ks < 2; ++ks){
    const bf16x8 af = *(const bf16x8*)&KT[(w*16 + lc)*72 + ks*32 + lg*8];
    #pragma unroll
    for (int n = 0; n < 4; ++n){
      const bf16x8 bf = *(const bf16x8*)&VT[(n*16 + lc)*72 + ks*32 + lg*8];
      acc[n] = __builtin_amdgcn_mfma_f32_16x16x32_bf16(af, bf, acc[n], 0, 0, 0);
    }
  }
  unsigned short* out = Tbuf + (size_t)blk*4096;
  #pragma unroll
  for (int n = 0; n < 4; ++n)
    #pragma unroll
    for (int r = 0; r < 4; ++r)
      out[(w*16 + lg*4 + r)*64 + n*16 + lc] = f2bf(acc[n][r]);
}

// Phase 2: scan, 128 blocks (bh x 4 quarters of d), bf16 T input
__global__ void chunk_scan(const unsigned short* __restrict__ Tbuf, unsigned short* __restrict__ statesT)
{
  const int bh = blockIdx.x, q = blockIdx.y, t = threadIdx.x;
  const int hh = bh & 15;
  const float gamma = 1.0f - exp2f(-5.0f - (float)hh);
  const float g64 = exp2f(log2f(gamma) * 64.0f);
  float S[4] = {0.f, 0.f, 0.f, 0.f};
  const int dv = t >> 2;                 // 0..63
  const int j0 = q*16 + (t & 3)*4;       // 4 d-elems
  for (int c = 0; c < 32; ++c){
    const size_t base = ((size_t)(bh*32 + c))*4096;
    ushort4 p; p.x = f2bf(S[0]); p.y = f2bf(S[1]); p.z = f2bf(S[2]); p.w = f2bf(S[3]);
    *(ushort4*)(statesT + base + dv*64 + j0) = p;
    #pragma unroll
    for (int j = 0; j < 4; ++j)
      S[j] = g64*S[j] + bf2f(Tbuf[base + (size_t)(j0 + j)*64 + dv]);
  }
}

__global__ __launch_bounds__(256, 2) void retention_chunk(
    const unsigned short* __restrict__ qb, const unsigned short* __restrict__ kb,
    const unsigned short* __restrict__ vb, const unsigned short* __restrict__ gb,
    const unsigned short* __restrict__ statesT, unsigned short* __restrict__ og)
{
  __shared__ unsigned short VT[64*72];
  __shared__ unsigned short Pw[64*72];
  const int t = threadIdx.x, w = t >> 6, ln = t & 63, lg = ln >> 4, lc = ln & 15;
  const int blk = blockIdx.x;          // bh*32 + c
  const int bh = blk >> 5, c = blk & 31;
  const int b = bh >> 4, hh = bh & 15;
  const float lg2g = log2f(1.0f - exp2f(-5.0f - (float)hh));
  float gpr[4];
  #pragma unroll
  for (int r = 0; r < 4; ++r) gpr[r] = exp2f(-lg2g * (float)r);   // gamma^{-r}
  const size_t rowbase = (size_t)(b*2048 + c*64);

  #pragma unroll
  for (int ch = 0; ch < 2; ++ch){
    const int chunk = ch*256 + t;
    const int i = chunk >> 3, d0 = (chunk & 7)*8;
    union {uint4 u; unsigned short s[8];} vv;
    vv.u = *(const uint4*)(vb + (rowbase + i)*1024 + hh*64 + d0);
    #pragma unroll
    for (int j = 0; j < 8; ++j) VT[(d0+j)*72 + i] = vv.s[j];
  }

  bf16x8 Qf[2], Kf[4][2];
  #pragma unroll
  for (int ks = 0; ks < 2; ++ks){
    union {uint4 u; bf16x8 f;} cv;
    cv.u = *(const uint4*)(qb + (rowbase + w*16 + lc)*1024 + hh*64 + ks*32 + lg*8);
    Qf[ks] = cv.f;
    #pragma unroll
    for (int mt = 0; mt < 4; ++mt){
      union {uint4 u; bf16x8 f;} kv;
      kv.u = *(const uint4*)(kb + (rowbase + mt*16 + lc)*1024 + hh*64 + ks*32 + lg*8);
      Kf[mt][ks] = kv.f;
    }
  }

  f32x4 st[4] = {};
  #pragma unroll
  for (int ks = 0; ks < 2; ++ks)
    #pragma unroll
    for (int mt = 0; mt < 4; ++mt)
      st[mt] = __builtin_amdgcn_mfma_f32_16x16x32_bf16(Kf[mt][ks], Qf[ks], st[mt], 0, 0, 0);

  __syncthreads();

  #pragma unroll
  for (int mt = 0; mt < 4; ++mt){
    const int kp = mt*16 + lg*4;
    const int qrow = w*16 + lc;
    const int delta0 = qrow - kp;
    const float dec0 = exp2f(lg2g * (float)delta0) * 0.125f;
    float vals[4];
    #pragma unroll
    for (int r = 0; r < 4; ++r)
      vals[r] = (delta0 >= r) ? st[mt][r] * dec0 * gpr[r] : 0.0f;
    uint2 pk; pk.x = packbf2(vals[0], vals[1]); pk.y = packbf2(vals[2], vals[3]);
    *(uint2*)&Pw[qrow*72 + kp] = pk;
  }

  f32x4 acc[4] = {};
  const unsigned short* Sbase = statesT + (size_t)blk*4096;
  #pragma unroll
  for (int ks = 0; ks < 2; ++ks)
    #pragma unroll
    for (int n = 0; n < 4; ++n){
      union {uint4 u; bf16x8 f;} sv;
      sv.u = *(const uint4*)(Sbase + (n*16 + lc)*64 + ks*32 + lg*8);
      acc[n] = __builtin_amdgcn_mfma_f32_16x16x32_bf16(Qf[ks], sv.f, acc[n], 0, 0, 0);
    }
  #pragma unroll
  for (int n = 0; n < 4; ++n)
    #pragma unroll
    for (int r = 0; r < 4; ++r)
      acc[n][r] *= exp2f(lg2g * (float)(w*16 + lg*4 + r)) * 0.125f;

  #pragma unroll
  for (int ks = 0; ks < 2; ++ks){
    const bf16x8 Pf = *(const bf16x8*)&Pw[(w*16 + lc)*72 + ks*32 + lg*8];
    #pragma unroll
    for (int n = 0; n < 4; ++n){
      const bf16x8 Vf = *(const bf16x8*)&VT[(n*16 + lc)*72 + ks*32 + lg*8];
      acc[n] = __builtin_amdgcn_mfma_f32_16x16x32_bf16(Pf, Vf, acc[n], 0, 0, 0);
    }
  }

  #pragma unroll
  for (int n = 0; n < 4; ++n){
    #pragma unroll
    for (int r = 0; r < 4; ++r){
      const size_t row = rowbase + w*16 + lg*4 + r;
      const int col = hh*64 + n*16 + lc;
      const float gv = bf2f(gb[row*1024 + col]);
      og[row*1024 + col] = f2bf(acc[n][r] * gv);
    }
  }
}

// ===== RVQ bf16 chain: argmin-from-partials + in-place residual update =====
// FINAL emits out = x2 + xn - nr  (x2, xn bf16)
template<int FINAL>
__global__ void rvq_update4(const unsigned short* __restrict__ cbbf_l,
                            const float2* __restrict__ partials,
                            unsigned short* __restrict__ resb, float* __restrict__ qlpart, int lvl,
                            const unsigned short* __restrict__ x2, const unsigned short* __restrict__ xn,
                            float* __restrict__ outf)
{
  const int m = blockIdx.x, t = threadIdx.x;
  __shared__ int sid;
  if (t == 0){
    float best = 3.4e38f; int bi = 0;
    #pragma unroll
    for (int p = 0; p < 16; ++p){
      const float2 pr = partials[m*16 + p];
      if (pr.x < best){ best = pr.x; bi = (int)pr.y; }
    }
    sid = bi;
  }
  __syncthreads();
  const int id = sid;
  const ushort4 qv = ((const ushort4*)(cbbf_l + (size_t)id*1024))[t];
  const ushort4 rv = ((const ushort4*)(resb + (size_t)m*1024))[t];
  const float n0 = bf2f(rv.x) - bf2f(qv.x);
  const float n1 = bf2f(rv.y) - bf2f(qv.y);
  const float n2 = bf2f(rv.z) - bf2f(qv.z);
  const float n3 = bf2f(rv.w) - bf2f(qv.w);
  if constexpr (FINAL){
    const size_t off = (size_t)m*256 + t;
    const ushort4 a = ((const ushort4*)x2)[off];
    const ushort4 b = ((const ushort4*)xn)[off];
    float4 o;
    o.x = bf2f(a.x) + bf2f(b.x) - n0;
    o.y = bf2f(a.y) + bf2f(b.y) - n1;
    o.z = bf2f(a.z) + bf2f(b.z) - n2;
    o.w = bf2f(a.w) + bf2f(b.w) - n3;
    ((float4*)outf)[off] = o;
  } else {
    ushort4 nb; nb.x = f2bf(n0); nb.y = f2bf(n1); nb.z = f2bf(n2); nb.w = f2bf(n3);
    ((ushort4*)(resb + (size_t)m*1024))[t] = nb;
  }
  float s = n0*n0 + n1*n1 + n2*n2 + n3*n3;
  #pragma unroll
  for (int o = 32; o >= 1; o >>= 1) s += __shfl_down(s, o);
  __shared__ float red[4];
  if ((t & 63) == 0) red[t >> 6] = s;
  __syncthreads();
  if (t == 0) qlpart[lvl*4096 + m] = red[0]+red[1]+red[2]+red[3];
}

__global__ void ql_final(const float* __restrict__ qlpart, float* __restrict__ outs)
{
  const int t = threadIdx.x;                     // 1024 threads
  float s = 0.f;
  for (int i = t; i < 16384; i += 1024) s += qlpart[i];
  #pragma unroll
  for (int o = 32; o >= 1; o >>= 1) s += __shfl_down(s, o);
  __shared__ float red[16];
  if ((t & 63) == 0) red[t >> 6] = s;
  __syncthreads();
  if (t == 0){
    float q = 0.f;
    #pragma unroll
    for (int i = 0; i < 16; ++i) q += red[i];
    q *= (1.0f/4194304.0f) * 0.25f;
    outs[0] = q; outs[1] = q;
  }
}

// ================= launcher =================
extern "C" void kernel_launch(void* const* d_in, const int* in_sizes, int n_in,
                              void* d_out, int out_size, void* d_ws, size_t ws_size,
                              hipStream_t stream)
{
  const float* x     = (const float*)d_in[0];
  const float* ln1_g = (const float*)d_in[1];
  const float* ln1_b = (const float*)d_in[2];
  const float* wq    = (const float*)d_in[3];
  const float* wk    = (const float*)d_in[4];
  const float* wv    = (const float*)d_in[5];
  const float* wg    = (const float*)d_in[6];
  const float* wo    = (const float*)d_in[7];
  const float* ln2_g = (const float*)d_in[8];
  const float* ln2_b = (const float*)d_in[9];
  const float* w1    = (const float*)d_in[10];
  const float* b1    = (const float*)d_in[11];
  const float* w2    = (const float*)d_in[12];
  const float* b2    = (const float*)d_in[13];
  const float* ln3_g = (const float*)d_in[14];
  const float* ln3_b = (const float*)d_in[15];
  const float* cb    = (const float*)d_in[16];

  char* ws = (char*)d_ws;
  const size_t MB = 1024*1024;
  unsigned short* wqkvgT = (unsigned short*)(ws + 0*MB);
  unsigned short* w1T  = (unsigned short*)(ws + 10*MB);
  unsigned short* w2T  = (unsigned short*)(ws + 18*MB);
  unsigned short* cbbf = (unsigned short*)(ws + 26*MB);
  float* cbn2     = (float*)(ws + 34*MB);
  float* qlpart   = (float*)(ws + 34*MB + 16*1024);
  float2* partials= (float2*)(ws + 34*MB + 128*1024);
  unsigned short* hbf  = (unsigned short*)(ws + 35*MB);
  unsigned short* qbuf = (unsigned short*)(ws + 43*MB);
  unsigned short* kbuf = (unsigned short*)(ws + 51*MB);
  unsigned short* vbuf = (unsigned short*)(ws + 59*MB);
  unsigned short* gbuf = (unsigned short*)(ws + 67*MB);
  unsigned short* skbuf = (unsigned short*)(ws + 43*MB);   // bf16 split-K partials x4 (32MB, reuses q/k/v/g)
  unsigned short* ogb  = (unsigned short*)(ws + 75*MB);
  unsigned short* x1b  = (unsigned short*)(ws + 83*MB);    // bf16 residual stream
  unsigned short* h2   = (unsigned short*)(ws + 99*MB);
  unsigned short* a1   = (unsigned short*)(ws + 107*MB);
  unsigned short* Tbuf = (unsigned short*)(ws + 139*MB);   // bf16, dead by MLP
  unsigned short* x2b  = (unsigned short*)(ws + 147*MB);   // bf16
  unsigned short* statesT = (unsigned short*)(ws + 155*MB);// dead by ln3 time
  unsigned short* xnb  = (unsigned short*)(ws + 163*MB);   // bf16 pristine xn
  unsigned short* resb = (unsigned short*)(ws + 171*MB);
  float2* rtab  = (float2*)(ws + 179*MB);

  float* outf = (float*)d_out;

  // --- fused weight prep + ln1 ---
  Ptr5 p5; p5.p[0]=wq; p5.p[1]=wk; p5.p[2]=wv; p5.p[3]=wg; p5.p[4]=wo;
  hipLaunchKernelGGL(prep_all, dim3(21760), dim3(256), 0, stream,
                     p5, wqkvgT, w1, w1T, w2, w2T, cb, cbbf, cbn2, rtab,
                     x, ln1_g, ln1_b, hbf);

  // --- retention sub-block ---
  hipLaunchKernelGGL((gemmf<3>), dim3(16,32), dim3(512), 0, stream,
                     hbf, wqkvgT, qbuf, (const float*)nullptr, (const float2*)rtab, 4096, 4096, 1024);
  hipLaunchKernelGGL(chunk_sum,  dim3(1024), dim3(256), 0, stream, kbuf, vbuf, Tbuf);
  hipLaunchKernelGGL(chunk_scan, dim3(32,4), dim3(256), 0, stream, Tbuf, statesT);
  hipLaunchKernelGGL(retention_chunk, dim3(1024), dim3(256), 0, stream,
                     qbuf, kbuf, vbuf, gbuf, statesT, ogb);
  hipLaunchKernelGGL((gemm64_bt<0,false,true,true>), dim3(8,64), dim3(256), 0, stream,
                     ogb, wqkvgT + 4194304, (void*)x1b, (const float*)nullptr, x, 4096, 1024, 1024);

  // --- MLP sub-block ---
  hipLaunchKernelGGL(ln_bf, dim3(4096), dim3(256), 0, stream, x1b, ln2_g, ln2_b, h2);
  hipLaunchKernelGGL((gemmf<2>), dim3(16,32), dim3(512), 0, stream,
                     h2, w1T, a1, b1, (const float2*)rtab, 4096, 4096, 1024);
  hipLaunchKernelGGL((gemm128_sk<4>), dim3(8,32,4), dim3(256), 0, stream,
                     a1, w2T, skbuf, 4096, 1024, 4096);
  hipLaunchKernelGGL(reduce_ln, dim3(4096), dim3(256), 0, stream,
                     skbuf, b2, x1b, x2b, ln3_g, ln3_b, resb, xnb);

  // --- RVQ (bf16 chain) ---
  for (int lvl = 0; lvl < 4; ++lvl){
    hipLaunchKernelGGL((gemm64_bt<4,false,false,false>), dim3(8,64), dim3(256), 0, stream,
                       resb, cbbf + (size_t)lvl*1048576, (void*)partials,
                       cbn2 + lvl*1024, (const float*)nullptr, 4096, 1024, 1024);
    if (lvl < 3)
      hipLaunchKernelGGL((rvq_update4<0>), dim3(4096), dim3(256), 0, stream,
                         cbbf + (size_t)lvl*1048576, partials, resb, qlpart, lvl,
                         (const unsigned short*)nullptr, (const unsigned short*)nullptr, (float*)nullptr);
    else
      hipLaunchKernelGGL((rvq_update4<1>), dim3(4096), dim3(256), 0, stream,
                         cbbf + (size_t)lvl*1048576, partials, resb, qlpart, lvl,
                         x2b, xnb, outf);
  }

  // --- outputs ---
  hipLaunchKernelGGL(ql_final, dim3(1), dim3(1024), 0, stream, qlpart, outf + 4194304);
}